// Round 3
// baseline (531.999 us; speedup 1.0000x reference)
//
#include <hip/hip_runtime.h>
#include <hip/hip_bf16.h>
#include <cstdint>
#include <cstddef>

#define K_DIM 4096
#define N_DIM 4096
#define BM 128
#define BN 128
#define BK 64   // halves per LDS row = 128 B = one full bank period

typedef __attribute__((ext_vector_type(8))) short short8;
typedef __attribute__((ext_vector_type(4))) float floatx4;
typedef __attribute__((ext_vector_type(16))) float floatx16;

__device__ __forceinline__ unsigned short f32_bf16_rne(float f) {
    union { float f; unsigned u; } v; v.f = f;
    unsigned r = (v.u + 0x7FFFu + ((v.u >> 16) & 1u)) >> 16;
    return (unsigned short)r;
}

// Fused fp32 -> bf16 cast for x and w. One 8-elem chunk per thread, exact grid.
__global__ __launch_bounds__(256) void cast2_f32_bf16_kernel(
        const float* __restrict__ x, const float* __restrict__ w,
        unsigned short* __restrict__ a16, unsigned short* __restrict__ b16,
        long nx, long nw) {
    const long nchunks = (nx + nw) / 8;
    const long c = (long)blockIdx.x * 256 + threadIdx.x;
    if (c >= nchunks) return;
    const long xc = nx / 8;
    const float* src;
    unsigned short* dst;
    if (c < xc) { long i = c * 8;        src = x + i; dst = a16 + i; }
    else        { long i = (c - xc) * 8; src = w + i; dst = b16 + i; }
    floatx4 a = *(const floatx4*)(src);
    floatx4 b = *(const floatx4*)(src + 4);
    union { unsigned short u[8]; short8 v; } r;
#pragma unroll
    for (int j = 0; j < 4; j++) r.u[j] = f32_bf16_rne(a[j]);
#pragma unroll
    for (int j = 0; j < 4; j++) r.u[4 + j] = f32_bf16_rne(b[j]);
    *(short8*)(dst) = r.v;
}

// bf16 GEMM, C = A * B^T. A: MxK bf16 row-major, B: NxK bf16 row-major, C: MxN fp32.
// 128x128 tile / 256 threads (4 waves 2x2). Each wave: 64x64 = 2x2 tiles of
// 32x32, via v_mfma_f32_32x32x16_bf16 (2382 TF ceiling vs 2075 for 16x16x32;
// 129 vs 155 MFMA-pipe cyc per BK=64 K-iter, half the instruction count).
// BK=64: LDS row = 128 B (full bank period). 16B blocks XOR-swizzled by row&7:
//   physical_blk = logical_kblk ^ (row & 7)
// => any 8 consecutive lanes of a 32-row fragment read hit 8 distinct 16B
// blocks = all 32 banks = conflict-free (verified 0 conflicts in R2).
// global_load_lds width=16 stages pre-swizzled: lane's source kblk permuted
// per-lane ((lane&7)^((lane>>3)&7)); LDS dest stays wave-uniform-base+lane*16.
__global__ __launch_bounds__(256) void gemm_bf16_bt(
        const unsigned short* __restrict__ A,
        const unsigned short* __restrict__ B,
        float* __restrict__ C, int M) {
    __shared__ unsigned short sA[BM * BK];   // 16 KiB
    __shared__ unsigned short sB[BN * BK];   // 16 KiB

    const int tid  = threadIdx.x;
    const int lane = tid & 63;
    const int wave = tid >> 6;   // 0..3
    const int wm   = wave >> 1;  // 0..1
    const int wn   = wave & 1;   // 0..1
    const int l32  = lane & 31;  // row within 32x32 tile
    const int khalf = lane >> 5; // 0..1: which 8-k half of K=16

    const int bm = blockIdx.y;
    const int bn = blockIdx.x;

    // ---- staging map (unchanged from R2) ----
    // issue i (0..3), wave w: rows i*32 + w*8 + (lane>>3); 8 rows x 128 B = 1 KiB.
    // lane writes LDS base + lane*16 -> physical blk (lane&7) of row (lane>>3);
    // source logical kblk = (lane&7) ^ ((lane>>3)&7) pre-applies the swizzle.
    const int srow     = wave * 8 + (lane >> 3);
    const int kblk_src = (lane & 7) ^ ((lane >> 3) & 7);

    const unsigned short* ag = A + ((size_t)bm * BM + srow) * K_DIM + kblk_src * 8;
    const unsigned short* bg = B + ((size_t)bn * BN + srow) * K_DIM + kblk_src * 8;

    floatx16 acc[2][2];
#pragma unroll
    for (int i = 0; i < 2; i++)
#pragma unroll
        for (int j = 0; j < 2; j++)
            acc[i][j] = (floatx16)0.0f;

    for (int k0 = 0; k0 < K_DIM; k0 += BK) {
        // ---- global -> LDS staging: 4 slabs x (A,B) ----
#pragma unroll
        for (int i = 0; i < 4; i++) {
            __builtin_amdgcn_global_load_lds(
                (const __attribute__((address_space(1))) void*)(ag + (size_t)(i * 32) * K_DIM),
                (__attribute__((address_space(3))) void*)(sA + (i * 32 + wave * 8) * BK),
                16, 0, 0);
            __builtin_amdgcn_global_load_lds(
                (const __attribute__((address_space(1))) void*)(bg + (size_t)(i * 32) * K_DIM),
                (__attribute__((address_space(3))) void*)(sB + (i * 32 + wave * 8) * BK),
                16, 0, 0);
        }
        ag += BK;
        bg += BK;
        __syncthreads();   // drains vmcnt (global_load_lds) + barrier

        // ---- 4 K-steps of 16: frags + 4 MFMA each ----
        // A-operand (32x32x16): A[m = lane&31][k = khalf*8 + j]
        // logical kblk = kk*2 + khalf; physical = logical ^ (row&7)
#pragma unroll
        for (int kk = 0; kk < 4; kk++) {
            const int pblk = ((kk * 2 + khalf) ^ (l32 & 7)) * 8;  // halves
            short8 af[2], bf[2];
#pragma unroll
            for (int mt = 0; mt < 2; mt++)
                af[mt] = *(const short8*)(sA + (wm * 64 + mt * 32 + l32) * BK + pblk);
#pragma unroll
            for (int nt = 0; nt < 2; nt++)
                bf[nt] = *(const short8*)(sB + (wn * 64 + nt * 32 + l32) * BK + pblk);
#pragma unroll
            for (int mt = 0; mt < 2; mt++)
#pragma unroll
                for (int nt = 0; nt < 2; nt++)
                    acc[mt][nt] = __builtin_amdgcn_mfma_f32_32x32x16_bf16(
                        af[mt], bf[nt], acc[mt][nt], 0, 0, 0);
        }
        __syncthreads();
    }

    // ---- epilogue: 32x32 C/D layout (m74/m101-verified):
    //      col = lane&31, row = (reg&3) + 8*(reg>>2) + 4*(lane>>5) ----
#pragma unroll
    for (int mt = 0; mt < 2; mt++) {
#pragma unroll
        for (int nt = 0; nt < 2; nt++) {
            const int col = bn * BN + wn * 64 + nt * 32 + l32;
            const size_t row0 = (size_t)bm * BM + wm * 64 + mt * 32 + 4 * khalf;
#pragma unroll
            for (int r = 0; r < 16; r++) {
                const size_t row = row0 + (r & 3) + 8 * (r >> 2);
                C[row * N_DIM + col] = acc[mt][nt][r];
            }
        }
    }
}

// Correctness fallback if ws_size too small for bf16 copies (fp32 vector ALU).
__global__ __launch_bounds__(256) void gemm_naive_f32(
        const float* __restrict__ X, const float* __restrict__ W,
        float* __restrict__ C, long total) {
    long idx = (long)blockIdx.x * 256 + threadIdx.x;
    if (idx >= total) return;
    const long row = idx / N_DIM, col = idx % N_DIM;
    const float* x = X + row * K_DIM;
    const float* w = W + col * K_DIM;
    float s = 0.f;
    for (int k = 0; k < K_DIM; k += 4) {
        floatx4 a = *(const floatx4*)(x + k);
        floatx4 b = *(const floatx4*)(w + k);
        s += a[0] * b[0] + a[1] * b[1] + a[2] * b[2] + a[3] * b[3];
    }
    C[idx] = s;
}

extern "C" void kernel_launch(void* const* d_in, const int* in_sizes, int n_in,
                              void* d_out, int out_size, void* d_ws, size_t ws_size,
                              hipStream_t stream) {
    const float* x = (const float*)d_in[0];   // (4,2048,4096) fp32
    const float* w = (const float*)d_in[1];   // (4096,4096) fp32, (N,K) = B^T layout
    float* out = (float*)d_out;               // (M, 4096) fp32

    const long nx = (long)in_sizes[0];        // M*K
    const long nw = (long)in_sizes[1];        // N*K
    const int  M  = (int)(nx / K_DIM);        // 8192

    const size_t a_bytes = (size_t)nx * 2;    // 64 MiB
    const size_t b_bytes = (size_t)nw * 2;    // 32 MiB

    if (ws_size >= a_bytes + b_bytes) {
        unsigned short* a16 = (unsigned short*)d_ws;
        unsigned short* b16 = (unsigned short*)((char*)d_ws + a_bytes);
        const long nchunks = (nx + nw) / 8;
        const int cast_blocks = (int)((nchunks + 255) / 256);
        cast2_f32_bf16_kernel<<<cast_blocks, 256, 0, stream>>>(x, w, a16, b16, nx, nw);
        dim3 grid(N_DIM / BN, M / BM);        // (32, 64)
        gemm_bf16_bt<<<grid, 256, 0, stream>>>(a16, b16, out, M);
    } else {
        const long total = (long)M * N_DIM;
        gemm_naive_f32<<<(int)((total + 255) / 256), 256, 0, stream>>>(x, w, out, total);
    }
}